// Round 12
// baseline (103.318 us; speedup 1.0000x reference)
//
#include <hip/hip_runtime.h>

// CoPE: gated reverse-cumsum positions + interpolated positional logits.
// B=2,H=16,S=2048,D=64,NPOS=64 -> 65536 rows of length 2048.
//
// Ladder: 164.7 (R1) -> 105.4 (R6: NT stores kill write-allocate)
//         -> 101.5 (R8) -> 99.7 (R10: fill-first; NT loads harmful).
// R11 FAILED correctness: __shfl (ds_bpermute) inside a divergent branch
// reads UNDEFINED data from exec-masked-off source lanes (pf=63 hits
// inactive lane 63). LESSON: on CDNA, keep cross-lane ops outside
// divergent control flow.
//
// R12 = R11 with interpolation hoisted out of the branch (all 64 lanes
// execute the shuffles; only the final store is predicated to 48 lanes).
// CH=192: sum of 192 sigmoids = 96 +- 3.2 (10 sigma above the 63 clamp);
// trims 19 MB of attn reads vs CH=256.

#define SLEN 2048
#define DDIM 64
#define NPOSN 64
#define ROWS (2 * 16 * 2048)
#define CH 192                  // columns in scan pass 1 (4 per lane, 48 lanes)
#define FILLN (SLEN - CH)       // 1856 = 7*256 + 64

typedef float vfloat4 __attribute__((ext_vector_type(4)));

__device__ __forceinline__ float sigmoidf_(float x) {
    return 1.0f / (1.0f + __expf(-x));
}

__global__ __launch_bounds__(256) void cope_kernel(
    const float* __restrict__ q,     // [65536, 64]
    const float* __restrict__ attn,  // [65536, 2048]
    const float* __restrict__ emb,   // [64, 64]
    float* __restrict__ out)         // [65536, 2048]
{
    __shared__ float semb[DDIM * NPOSN];   // 16 KiB
    {
        const float4* __restrict__ src = (const float4*)emb;
        float4* __restrict__ dst = (float4*)semb;
        #pragma unroll
        for (int t = 0; t < 4; ++t)
            dst[threadIdx.x + 256 * t] = src[threadIdx.x + 256 * t];
    }
    __syncthreads();

    const int lane = threadIdx.x & 63;
    const int wave = threadIdx.x >> 6;
    const int r_u = __builtin_amdgcn_readfirstlane(blockIdx.x * 4 + wave);

    const float* __restrict__ arow = attn + (size_t)r_u * SLEN;
    float* __restrict__ orow = out + (size_t)r_u * SLEN;

    // prefetch scan chunk [FILLN, SLEN): lanes 0-47 own 4 cols each
    float4 cur = make_float4(0.f, 0.f, 0.f, 0.f);
    if (lane < CH / 4)
        cur = *reinterpret_cast<const float4*>(arow + FILLN + lane * 4);

    // einsum: lv = logits_int[r][lane]; qrow[d] is a true s_load (r_u SGPR)
    const float* __restrict__ qrow = q + (size_t)r_u * DDIM;
    float a0 = 0.0f, a1 = 0.0f;
    #pragma unroll
    for (int d = 0; d < DDIM; d += 2) {
        a0 = fmaf(qrow[d],     semb[d * NPOSN + lane],       a0);
        a1 = fmaf(qrow[d + 1], semb[(d + 1) * NPOSN + lane], a1);
    }
    const float lv  = a0 + a1;
    const float l63 = __shfl(lv, NPOSN - 1);

    // ---- fill-first: [0, FILLN) = l63 ----
    const vfloat4 v4 = { l63, l63, l63, l63 };
    #pragma unroll
    for (int k = 0; k < FILLN / 256; ++k)
        __builtin_nontemporal_store(v4,
            reinterpret_cast<vfloat4*>(orow + k * 256 + lane * 4));
    if (lane < (FILLN % 256) / 4)   // tail [1792, 1856): 16 lanes
        __builtin_nontemporal_store(v4,
            reinterpret_cast<vfloat4*>(orow + (FILLN / 256) * 256 + lane * 4));

    // ---- scan pass 1 on [FILLN, SLEN); lanes >= 48 carry zero gates ----
    float g0 = 0.f, g1 = 0.f, g2 = 0.f, g3 = 0.f;
    if (lane < CH / 4) {
        g0 = sigmoidf_(cur.x);
        g1 = sigmoidf_(cur.y);
        g2 = sigmoidf_(cur.z);
        g3 = sigmoidf_(cur.w);
    }
    const float l3 = g3;
    const float l2 = g2 + l3;
    const float l1 = g1 + l2;
    const float l0 = g0 + l1;              // lane total (0 for lanes >= 48)
    float s = l0;                           // wave reverse inclusive scan
    #pragma unroll
    for (int off = 1; off < 64; off <<= 1) {
        const float t = __shfl_down(s, off);
        if (lane + off < 64) s += t;
    }
    const float excl = s - l0;             // suffix strictly right of lane
    const float T    = __shfl(s, 0);       // region total

    // interpolation: ALL 64 lanes execute (shuffles need full exec mask);
    // lanes >= 48 compute a harmless pos=0 path and skip the store.
    vfloat4 o;
    {
        const float pos = fminf(excl + l0, 63.0f);
        const float pf = floorf(pos), w = pos - pf;
        o.x = __shfl(lv, (int)ceilf(pos)) * w + __shfl(lv, (int)pf) * (1.0f - w);
    }
    {
        const float pos = fminf(excl + l1, 63.0f);
        const float pf = floorf(pos), w = pos - pf;
        o.y = __shfl(lv, (int)ceilf(pos)) * w + __shfl(lv, (int)pf) * (1.0f - w);
    }
    {
        const float pos = fminf(excl + l2, 63.0f);
        const float pf = floorf(pos), w = pos - pf;
        o.z = __shfl(lv, (int)ceilf(pos)) * w + __shfl(lv, (int)pf) * (1.0f - w);
    }
    {
        const float pos = fminf(excl + l3, 63.0f);
        const float pf = floorf(pos), w = pos - pf;
        o.w = __shfl(lv, (int)ceilf(pos)) * w + __shfl(lv, (int)pf) * (1.0f - w);
    }
    if (lane < CH / 4)
        __builtin_nontemporal_store(o,
            reinterpret_cast<vfloat4*>(orow + FILLN + lane * 4));

    // ---- slow path: only if carry after pass 1 < 63 (10-sigma; correctness) ----
    float carry = T;
    int jb = FILLN;
    if (carry < 63.0f && jb > 0) {
        __builtin_amdgcn_s_waitcnt(0);     // drain fill stores before overwrite
        while (carry < 63.0f && jb > 0) {
            jb -= 64;
            float sg = sigmoidf_(arow[jb + lane]);
            #pragma unroll
            for (int off = 1; off < 64; off <<= 1) {
                const float t = __shfl_down(sg, off);
                if (lane + off < 64) sg += t;
            }
            const float pos = fminf(carry + sg, 63.0f);
            const float pf = floorf(pos), w = pos - pf;
            const float lf = __shfl(lv, (int)pf);
            const float lc = __shfl(lv, (int)ceilf(pos));
            __builtin_nontemporal_store(lc * w + lf * (1.0f - w), orow + jb + lane);
            carry += __shfl(sg, 0);
        }
    }
}

extern "C" void kernel_launch(void* const* d_in, const int* in_sizes, int n_in,
                              void* d_out, int out_size, void* d_ws, size_t ws_size,
                              hipStream_t stream) {
    const float* q    = (const float*)d_in[0];
    const float* attn = (const float*)d_in[1];
    const float* emb  = (const float*)d_in[2];
    float* out = (float*)d_out;

    dim3 grid(ROWS / 4), block(256);
    cope_kernel<<<grid, block, 0, stream>>>(q, attn, emb, out);
}

// Round 13
// 99.341 us; speedup vs baseline: 1.0400x; 1.0400x over previous
//
#include <hip/hip_runtime.h>

// CoPE: gated reverse-cumsum positions + interpolated positional logits.
// B=2,H=16,S=2048,D=64,NPOS=64 -> 65536 rows of length 2048.
//
// FINAL (= R10, best verified: 99.7 us, eff. BW 6.22 TB/s vs 6.36-6.82
// pure-write fill band on the same chip).
// Ladder: 164.7 (R1 naive+early-exit) -> 105.4 (R6: NT stores kill
// write-allocate, the single biggest lever) -> 101.5 (R8: LDS emb +
// scalar q loads + one-pass 256-col scan) -> 99.7 (R10: fill-first).
// Measured dead ends: NT loads (132-138 us), CH=192 predicated scan
// (103.3), RPW=4 batching (171), kernel split (197).
// Durable gfx950 lessons: (1) store-dominated kernels need
// __builtin_nontemporal_store (write-allocate otherwise fetches every
// output line); (2) nontemporal LOADS are harmful; (3) __shfl inside
// divergent branches reads undefined data from inactive lanes.

#define SLEN 2048
#define DDIM 64
#define NPOSN 64
#define ROWS (2 * 16 * 2048)
#define CH 256                  // columns in scan pass 1 (4 per lane)

typedef float vfloat4 __attribute__((ext_vector_type(4)));

__device__ __forceinline__ float sigmoidf_(float x) {
    return 1.0f / (1.0f + __expf(-x));
}

__global__ __launch_bounds__(256) void cope_kernel(
    const float* __restrict__ q,     // [65536, 64]
    const float* __restrict__ attn,  // [65536, 2048]
    const float* __restrict__ emb,   // [64, 64]
    float* __restrict__ out)         // [65536, 2048]
{
    __shared__ float semb[DDIM * NPOSN];   // 16 KiB
    {
        const float4* __restrict__ src = (const float4*)emb;
        float4* __restrict__ dst = (float4*)semb;
        #pragma unroll
        for (int t = 0; t < 4; ++t)
            dst[threadIdx.x + 256 * t] = src[threadIdx.x + 256 * t];
    }
    __syncthreads();

    const int lane = threadIdx.x & 63;
    const int wave = threadIdx.x >> 6;
    const int r_u = __builtin_amdgcn_readfirstlane(blockIdx.x * 4 + wave);

    const float* __restrict__ arow = attn + (size_t)r_u * SLEN;
    float* __restrict__ orow = out + (size_t)r_u * SLEN;

    // prefetch scan chunk [SLEN-CH, SLEN), 4 consecutive cols per lane
    // (plain cached load -- NT loads measurably regress on gfx950)
    const float4 cur = *reinterpret_cast<const float4*>(arow + SLEN - CH + lane * 4);

    // einsum: lv = logits_int[r][lane]; qrow[d] is a true s_load (r_u SGPR)
    const float* __restrict__ qrow = q + (size_t)r_u * DDIM;
    float a0 = 0.0f, a1 = 0.0f;
    #pragma unroll
    for (int d = 0; d < DDIM; d += 2) {
        a0 = fmaf(qrow[d],     semb[d * NPOSN + lane],       a0);
        a1 = fmaf(qrow[d + 1], semb[(d + 1) * NPOSN + lane], a1);
    }
    const float lv  = a0 + a1;
    const float l63 = __shfl(lv, NPOSN - 1);

    // ---- fill-first: [0, SLEN-CH) = l63 (scan pass 1 always covers the
    // unclamped region for this data; slow path overwrites if not) ----
    const vfloat4 v4 = { l63, l63, l63, l63 };
    #pragma unroll
    for (int k = 0; k < (SLEN - CH) / 256; ++k)
        __builtin_nontemporal_store(v4,
            reinterpret_cast<vfloat4*>(orow + k * 256 + lane * 4));

    // ---- scan pass 1 on [SLEN-CH, SLEN) ----
    const float g0 = sigmoidf_(cur.x);
    const float g1 = sigmoidf_(cur.y);
    const float g2 = sigmoidf_(cur.z);
    const float g3 = sigmoidf_(cur.w);
    const float l3 = g3;
    const float l2 = g2 + l3;
    const float l1 = g1 + l2;
    const float l0 = g0 + l1;              // lane total
    float s = l0;                           // wave reverse inclusive scan
    #pragma unroll
    for (int off = 1; off < 64; off <<= 1) {
        const float t = __shfl_down(s, off);
        if (lane + off < 64) s += t;
    }
    const float excl = s - l0;             // suffix strictly right of lane
    const float T    = __shfl(s, 0);       // chunk total

    vfloat4 o;
    {
        const float pos = fminf(excl + l0, 63.0f);
        const float pf = floorf(pos), w = pos - pf;
        o.x = __shfl(lv, (int)ceilf(pos)) * w + __shfl(lv, (int)pf) * (1.0f - w);
    }
    {
        const float pos = fminf(excl + l1, 63.0f);
        const float pf = floorf(pos), w = pos - pf;
        o.y = __shfl(lv, (int)ceilf(pos)) * w + __shfl(lv, (int)pf) * (1.0f - w);
    }
    {
        const float pos = fminf(excl + l2, 63.0f);
        const float pf = floorf(pos), w = pos - pf;
        o.z = __shfl(lv, (int)ceilf(pos)) * w + __shfl(lv, (int)pf) * (1.0f - w);
    }
    {
        const float pos = fminf(excl + l3, 63.0f);
        const float pf = floorf(pos), w = pos - pf;
        o.w = __shfl(lv, (int)ceilf(pos)) * w + __shfl(lv, (int)pf) * (1.0f - w);
    }
    __builtin_nontemporal_store(o,
        reinterpret_cast<vfloat4*>(orow + SLEN - CH + lane * 4));

    // ---- slow path: only if carry after pass 1 < 63 (P ~ 0; correctness) ----
    float carry = T;
    int jb = SLEN - CH;
    if (carry < 63.0f && jb > 0) {
        __builtin_amdgcn_s_waitcnt(0);     // drain fill stores before overwrite
        while (carry < 63.0f && jb > 0) {
            jb -= 64;
            float sg = sigmoidf_(arow[jb + lane]);
            #pragma unroll
            for (int off = 1; off < 64; off <<= 1) {
                const float t = __shfl_down(sg, off);
                if (lane + off < 64) sg += t;
            }
            const float pos = fminf(carry + sg, 63.0f);
            const float pf = floorf(pos), w = pos - pf;
            const float lf = __shfl(lv, (int)pf);
            const float lc = __shfl(lv, (int)ceilf(pos));
            __builtin_nontemporal_store(lc * w + lf * (1.0f - w), orow + jb + lane);
            carry += __shfl(sg, 0);
        }
    }
}

extern "C" void kernel_launch(void* const* d_in, const int* in_sizes, int n_in,
                              void* d_out, int out_size, void* d_ws, size_t ws_size,
                              hipStream_t stream) {
    const float* q    = (const float*)d_in[0];
    const float* attn = (const float*)d_in[1];
    const float* emb  = (const float*)d_in[2];
    float* out = (float*)d_out;

    dim3 grid(ROWS / 4), block(256);
    cope_kernel<<<grid, block, 0, stream>>>(q, attn, emb, out);
}